// Round 3
// baseline (1708.584 us; speedup 1.0000x reference)
//
#include <hip/hip_runtime.h>
#include <math.h>

#define NT 100000
#define B_GRAPHS 50
#define NE 1600000
#define V 15000
#define D 128
#define NODES_PER_GRAPH (NT / B_GRAPHS)   // 2000

#define CHUNK 1024
#define NCHUNK ((NT + CHUNK - 1) / CHUNK) // 98

#define A2_BLOCKS 512
#define POOL_N (B_GRAPHS * D + B_GRAPHS)  // 6450
#define A2_STRIDE 6464                    // padded partial stride

// ---- bf16x2 helpers: pack (RN-to-even) / unpack; lo=dim l, hi=dim l+64 ----
__device__ inline unsigned pack_bf16x2(float a, float b) {
  unsigned ua = __float_as_uint(a), ub = __float_as_uint(b);
  unsigned ra = (ua + 0x7fffu + ((ua >> 16) & 1u)) >> 16;
  unsigned rb = (ub + 0x7fffu + ((ub >> 16) & 1u)) >> 16;
  return (ra & 0xffffu) | (rb << 16);
}
__device__ inline float2 unpack_bf16x2(unsigned v) {
  return make_float2(__uint_as_float(v << 16), __uint_as_float(v & 0xffff0000u));
}

// ---------- K1: P1p = bf16x2-permuted (embeds @ W1 + b1)  [V, 64 dwords] ----------
#define PROJ_ROWS 32
__global__ void k_project(const float* __restrict__ embeds,
                          const float* __restrict__ W1,
                          const float* __restrict__ b1,
                          unsigned* __restrict__ P1p) {
  __shared__ float sE[PROJ_ROWS][D];   // 16 KB
  int t = threadIdx.x;                 // 0..127 = output column
  int row0 = blockIdx.x * PROJ_ROWS;
  for (int i = t; i < PROJ_ROWS * D; i += 128) {
    int r = i >> 7, c = i & 127;
    int v = row0 + r;
    sE[r][c] = (v < V) ? embeds[(size_t)v * D + c] : 0.f;
  }
  __syncthreads();
  float bd = b1[t];
  float acc[PROJ_ROWS];
#pragma unroll
  for (int r = 0; r < PROJ_ROWS; ++r) acc[r] = bd;
#pragma unroll 4
  for (int k = 0; k < D; ++k) {
    float w = W1[k * D + t];           // coalesced; 64 KB, L2-resident
#pragma unroll
    for (int r = 0; r < PROJ_ROWS; ++r) acc[r] = fmaf(sE[r][k], w, acc[r]);
  }
  __syncthreads();                     // done with sE as input
#pragma unroll
  for (int r = 0; r < PROJ_ROWS; ++r) sE[r][t] = acc[r];
  __syncthreads();
  for (int i = t; i < PROJ_ROWS * 64; i += 128) {
    int r = i >> 6, l = i & 63;
    int v = row0 + r;
    if (v < V) P1p[(size_t)v * 64 + l] = pack_bf16x2(sE[r][l], sE[r][64 + l]);
  }
}

// ---------- K2: both degree counts in one pass ----------
__global__ void k_count2(const int* __restrict__ src, const int* __restrict__ dst,
                         int* __restrict__ cntS, int* __restrict__ cntD) {
  int e = blockIdx.x * blockDim.x + threadIdx.x;
  if (e < NE) {
    atomicAdd(&cntS[src[e]], 1);
    atomicAdd(&cntD[dst[e]], 1);
  }
}

// ---------- K3..K5: count -> exclusive scan (two-level) ----------
__global__ void k_chunksum(const int* __restrict__ counts, int* __restrict__ chunkSum) {
  __shared__ int red[256];
  int c = blockIdx.x, t = threadIdx.x;
  int base = c * CHUNK + t * 4;
  int s = 0;
#pragma unroll
  for (int i = 0; i < 4; ++i) { int idx = base + i; if (idx < NT) s += counts[idx]; }
  red[t] = s; __syncthreads();
  for (int off = 128; off > 0; off >>= 1) {
    if (t < off) red[t] += red[t + off];
    __syncthreads();
  }
  if (t == 0) chunkSum[c] = red[0];
}

__global__ void k_scanchunks(const int* __restrict__ chunkSum, int* __restrict__ chunkOff) {
  __shared__ int s[128];
  int t = threadIdx.x;                 // 128 threads
  int v = (t < NCHUNK) ? chunkSum[t] : 0;
  s[t] = v; __syncthreads();
  for (int off = 1; off < 128; off <<= 1) {
    int x = (t >= off) ? s[t - off] : 0;
    __syncthreads();
    s[t] += x;
    __syncthreads();
  }
  if (t < NCHUNK) chunkOff[t] = s[t] - v;   // exclusive
}

__global__ void k_scan_write(const int* __restrict__ counts, const int* __restrict__ chunkOff,
                             int* __restrict__ row_start) {
  __shared__ int s[256];
  int c = blockIdx.x, t = threadIdx.x;
  int base = c * CHUNK + t * 4;
  int c0 = 0, c1 = 0, c2 = 0, c3 = 0;
  if (base + 0 < NT) c0 = counts[base + 0];
  if (base + 1 < NT) c1 = counts[base + 1];
  if (base + 2 < NT) c2 = counts[base + 2];
  if (base + 3 < NT) c3 = counts[base + 3];
  int tsum = c0 + c1 + c2 + c3;
  s[t] = tsum; __syncthreads();
  for (int off = 1; off < 256; off <<= 1) {
    int x = (t >= off) ? s[t - off] : 0;
    __syncthreads();
    s[t] += x;
    __syncthreads();
  }
  int toff = s[t] - tsum + chunkOff[c];
  if (base + 0 < NT) row_start[base + 0] = toff;
  if (base + 1 < NT) row_start[base + 1] = toff + c0;
  if (base + 2 < NT) row_start[base + 2] = toff + c0 + c1;
  if (base + 3 < NT) row_start[base + 3] = toff + c0 + c1 + c2;
}

// ---------- K6: fill BOTH CSR payloads in one pass ----------
// payD[posD] = (node_ids[src], w)        -- dst-keyed, for layer-1 gather
// payS[posS] = (graph(dst), w/deg[dst])  -- src-keyed, for layer-2 scatter
__global__ void k_fill2(const int* __restrict__ src, const int* __restrict__ dst,
                        const float* __restrict__ ew, const int* __restrict__ node_ids,
                        const int* __restrict__ rowD, int* __restrict__ curD,
                        const int* __restrict__ cntD,
                        const int* __restrict__ rowS, int* __restrict__ curS,
                        int2* __restrict__ payD, int2* __restrict__ payS) {
  int e = blockIdx.x * blockDim.x + threadIdx.x;
  if (e >= NE) return;
  int s = src[e], d = dst[e];
  float w = ew[e];
  int wid = node_ids[s];
  int pd = rowD[d] + atomicAdd(&curD[d], 1);
  payD[pd] = make_int2(wid, __float_as_int(w));
  int g = d / NODES_PER_GRAPH;
  float cf = w / (float)cntD[d];          // deg >= 1 since edge e exists
  int ps = rowS[s] + atomicAdd(&curS[s], 1);
  payS[ps] = make_int2(g, __float_as_int(cf));
}

// ---------- K7: layer-1 aggregate + mean + leaky_relu -> h1p (bf16x2 permuted) ----------
// one wave per dst node; lane l holds dims (l, l+64); pipelined gather
__global__ void k_agg1(const int2* __restrict__ payD,
                       const int* __restrict__ rowD, const int* __restrict__ cntD,
                       const unsigned* __restrict__ P1p,
                       unsigned* __restrict__ h1p) {
  int n = blockIdx.x * 4 + (threadIdx.x >> 6);
  int l = threadIdx.x & 63;
  int beg = rowD[n];
  int cnt = cntD[n];
  float ax = 0.f, ay = 0.f;
  int2 pA = (cnt > 0) ? payD[beg] : make_int2(0, 0);
  int2 pB = (cnt > 1) ? payD[beg + 1] : make_int2(0, 0);
  unsigned vA = (cnt > 0) ? P1p[(size_t)pA.x * 64 + l] : 0u;
  for (int j = 0; j < cnt; ++j) {
    unsigned vB = (j + 1 < cnt) ? P1p[(size_t)pB.x * 64 + l] : 0u;  // in flight
    int2 pC = (j + 2 < cnt) ? payD[beg + j + 2] : make_int2(0, 0);
    float w = __int_as_float(pA.y);
    float2 v = unpack_bf16x2(vA);
    ax = fmaf(w, v.x, ax);
    ay = fmaf(w, v.y, ay);
    pA = pB; pB = pC; vA = vB;
  }
  float inv = (cnt > 0) ? (1.0f / (float)cnt) : 0.0f;
  float x0 = ax * inv, x1 = ay * inv;
  x0 = (x0 > 0.f) ? x0 : 0.01f * x0;   // leaky_relu(0)=0 so deg==0 rows stay 0
  x1 = (x1 > 0.f) ? x1 : 0.01f * x1;
  h1p[(size_t)n * 64 + l] = pack_bf16x2(x0, x1);
}

// ---------- K8: layer-2 src-centric scatter into LDS pool; no random gathers ----------
__global__ void k_agg2(const int2* __restrict__ payS,
                       const int* __restrict__ rowS, const int* __restrict__ cntS,
                       const unsigned* __restrict__ h1p,
                       float* __restrict__ partials) {
  __shared__ float sP[POOL_N];          // 50*128 poolS + 50 poolC = 25.8 KB
  for (int i = threadIdx.x; i < POOL_N; i += 256) sP[i] = 0.f;
  __syncthreads();
  int l = threadIdx.x & 63, w = threadIdx.x >> 6;
  const int npb = (NT + A2_BLOCKS - 1) / A2_BLOCKS;   // 196
  int base = blockIdx.x * npb;
  int end = base + npb; if (end > NT) end = NT;
  for (int n = base + w; n < end; n += 4) {
    int beg = rowS[n], cnt = cntS[n];
    if (cnt == 0) continue;
    float2 hv = unpack_bf16x2(h1p[(size_t)n * 64 + l]);  // own row, sequential
    int2 p = payS[beg];
    for (int j = 0; j < cnt; ++j) {
      int2 pn = (j + 1 < cnt) ? payS[beg + j + 1] : p;   // prefetch
      float c = __int_as_float(p.y);
      int go = p.x * D;
      atomicAdd(&sP[go + l], c * hv.x);        // bank = l%32: 2-way, free
      atomicAdd(&sP[go + 64 + l], c * hv.y);
      if (l == 0) atomicAdd(&sP[B_GRAPHS * D + p.x], c);
      p = pn;
    }
  }
  __syncthreads();
  float* dstp = partials + (size_t)blockIdx.x * A2_STRIDE;
  for (int i = threadIdx.x; i < POOL_N; i += 256) dstp[i] = sP[i];
}

// ---------- K8b: reduce partials -> pool[6450] ----------
__global__ void k_reduce(const float* __restrict__ partials, float* __restrict__ pool) {
  int j = blockIdx.x * 256 + threadIdx.x;     // 0..6655
  if (j >= POOL_N) return;
  const int per = A2_BLOCKS / 8;               // 64 partial-blocks per slice
  const float* p = partials + (size_t)blockIdx.y * per * A2_STRIDE + j;
  float s = 0.f;
#pragma unroll 4
  for (int b = 0; b < per; ++b) s += p[(size_t)b * A2_STRIDE];
  atomicAdd(&pool[j], s);
}

// ---------- K9: head ----------
__global__ void k_final(const float* __restrict__ poolS, const float* __restrict__ poolC,
                        const float* __restrict__ W2, const float* __restrict__ b2,
                        const float* __restrict__ W_out, const float* __restrict__ b_out,
                        const float* __restrict__ y, float* __restrict__ out) {
  int t = threadIdx.x;  // 128 threads
  __shared__ float w2o[D];
  __shared__ float red[D];
  __shared__ float s2o_sh;
  __shared__ float logits[B_GRAPHS];
  float acc = 0.f;
  for (int d = 0; d < D; ++d) acc = fmaf(W2[t * D + d], W_out[d], acc);
  w2o[t] = acc;
  red[t] = b2[t] * W_out[t];
  __syncthreads();
  for (int off = 64; off > 0; off >>= 1) {
    if (t < off) red[t] += red[t + off];
    __syncthreads();
  }
  if (t == 0) s2o_sh = red[0];
  __syncthreads();
  float s2o = s2o_sh;
  float bout = b_out[0];
  const float invN = 1.0f / (float)NODES_PER_GRAPH;
  for (int g = 0; g < B_GRAPHS; ++g) {
    red[t] = poolS[g * D + t] * w2o[t];
    __syncthreads();
    for (int off = 64; off > 0; off >>= 1) {
      if (t < off) red[t] += red[t + off];
      __syncthreads();
    }
    if (t == 0) logits[g] = red[0] * invN + poolC[g] * invN * s2o + bout;
    __syncthreads();
  }
  float term = 0.f;
  if (t < B_GRAPHS) {
    float l = logits[t];
    out[1 + t] = 1.0f / (1.0f + expf(-l));            // y_pred
    term = fmaxf(l, 0.f) - l * y[t] + log1pf(expf(-fabsf(l)));
  }
  red[t] = term;
  __syncthreads();
  for (int off = 64; off > 0; off >>= 1) {
    if (t < off) red[t] += red[t + off];
    __syncthreads();
  }
  if (t == 0) out[0] = red[0] / (float)B_GRAPHS;      // loss
}

extern "C" void kernel_launch(void* const* d_in, const int* in_sizes, int n_in,
                              void* d_out, int out_size, void* d_ws, size_t ws_size,
                              hipStream_t stream) {
  const int*   node_ids = (const int*)d_in[0];
  const int*   src      = (const int*)d_in[1];
  const int*   dst      = (const int*)d_in[2];
  const float* ew       = (const float*)d_in[3];
  const float* y        = (const float*)d_in[4];
  const float* embeds   = (const float*)d_in[5];
  const float* W1       = (const float*)d_in[6];
  const float* b1       = (const float*)d_in[7];
  const float* W2       = (const float*)d_in[8];
  const float* b2       = (const float*)d_in[9];
  const float* W_out    = (const float*)d_in[10];
  const float* b_out    = (const float*)d_in[11];
  float* out = (float*)d_out;
  (void)in_sizes; (void)n_in; (void)out_size; (void)ws_size;

  char* ws = (char*)d_ws;
  size_t off = 0;
  auto alloc = [&](size_t bytes) {
    size_t r = off;
    off = (off + bytes + 511) & ~(size_t)511;
    return r;
  };
  // zero region (poisoned 0xAA before every call)
  size_t o_cntD  = alloc((size_t)NT * 4);
  size_t o_cntS  = alloc((size_t)NT * 4);
  size_t o_curD  = alloc((size_t)NT * 4);
  size_t o_curS  = alloc((size_t)NT * 4);
  size_t o_pool  = alloc((size_t)POOL_N * 4);
  size_t zero_end = off;
  // non-zeroed
  size_t o_rowD  = alloc((size_t)NT * 4);
  size_t o_rowS  = alloc((size_t)NT * 4);
  size_t o_csum  = alloc(128 * 4);
  size_t o_coff  = alloc(128 * 4);
  size_t o_P1p   = alloc((size_t)V * 64 * 4);          // 3.84 MB
  size_t o_payD  = alloc((size_t)NE * 8);              // 12.8 MB
  size_t o_payS  = alloc((size_t)NE * 8);              // 12.8 MB
  size_t o_h1p   = alloc((size_t)NT * 64 * 4);         // 25.6 MB
  size_t o_part  = alloc((size_t)A2_BLOCKS * A2_STRIDE * 4);  // 13.2 MB

  int*      cntD    = (int*)(ws + o_cntD);
  int*      cntS    = (int*)(ws + o_cntS);
  int*      curD    = (int*)(ws + o_curD);
  int*      curS    = (int*)(ws + o_curS);
  float*    pool    = (float*)(ws + o_pool);
  int*      rowD    = (int*)(ws + o_rowD);
  int*      rowS    = (int*)(ws + o_rowS);
  int*      chunkSum= (int*)(ws + o_csum);
  int*      chunkOff= (int*)(ws + o_coff);
  unsigned* P1p     = (unsigned*)(ws + o_P1p);
  int2*     payD    = (int2*)(ws + o_payD);
  int2*     payS    = (int2*)(ws + o_payS);
  unsigned* h1p     = (unsigned*)(ws + o_h1p);
  float*    partials= (float*)(ws + o_part);

  hipMemsetAsync(ws, 0, zero_end, stream);

  k_project<<<(V + PROJ_ROWS - 1) / PROJ_ROWS, 128, 0, stream>>>(embeds, W1, b1, P1p);
  k_count2<<<(NE + 255) / 256, 256, 0, stream>>>(src, dst, cntS, cntD);
  // dst-CSR offsets
  k_chunksum<<<NCHUNK, 256, 0, stream>>>(cntD, chunkSum);
  k_scanchunks<<<1, 128, 0, stream>>>(chunkSum, chunkOff);
  k_scan_write<<<NCHUNK, 256, 0, stream>>>(cntD, chunkOff, rowD);
  // src-CSR offsets
  k_chunksum<<<NCHUNK, 256, 0, stream>>>(cntS, chunkSum);
  k_scanchunks<<<1, 128, 0, stream>>>(chunkSum, chunkOff);
  k_scan_write<<<NCHUNK, 256, 0, stream>>>(cntS, chunkOff, rowS);
  // fill both payloads
  k_fill2<<<(NE + 255) / 256, 256, 0, stream>>>(src, dst, ew, node_ids,
                                                rowD, curD, cntD, rowS, curS, payD, payS);
  k_agg1<<<NT / 4, 256, 0, stream>>>(payD, rowD, cntD, P1p, h1p);
  k_agg2<<<A2_BLOCKS, 256, 0, stream>>>(payS, rowS, cntS, h1p, partials);
  {
    dim3 g((POOL_N + 255) / 256, 8);
    k_reduce<<<g, 256, 0, stream>>>(partials, pool);
  }
  k_final<<<1, 128, 0, stream>>>(pool, pool + B_GRAPHS * D, W2, b2, W_out, b_out, y, out);
}

// Round 4
// 756.370 us; speedup vs baseline: 2.2589x; 2.2589x over previous
//
#include <hip/hip_runtime.h>
#include <math.h>

#define NT 100000
#define B_GRAPHS 50
#define NE 1600000
#define V 15000
#define D 128
#define NODES_PER_GRAPH (NT / B_GRAPHS)   // 2000

#define CHUNK 1024
#define NCHUNK ((NT + CHUNK - 1) / CHUNK) // 98

#define POOL_N (B_GRAPHS * D + B_GRAPHS)  // 6450

// ---- bf16x2 helpers: pack (RN-to-even) / unpack; lo=dim l, hi=dim l+64 ----
__device__ inline unsigned pack_bf16x2(float a, float b) {
  unsigned ua = __float_as_uint(a), ub = __float_as_uint(b);
  unsigned ra = (ua + 0x7fffu + ((ua >> 16) & 1u)) >> 16;
  unsigned rb = (ub + 0x7fffu + ((ub >> 16) & 1u)) >> 16;
  return (ra & 0xffffu) | (rb << 16);
}
__device__ inline float2 unpack_bf16x2(unsigned v) {
  return make_float2(__uint_as_float(v << 16), __uint_as_float(v & 0xffff0000u));
}

// ---------- K1: P1p = bf16x2-permuted (embeds @ W1 + b1)  [V, 64 dwords] ----------
#define PROJ_ROWS 32
__global__ void k_project(const float* __restrict__ embeds,
                          const float* __restrict__ W1,
                          const float* __restrict__ b1,
                          unsigned* __restrict__ P1p) {
  __shared__ float sE[PROJ_ROWS][D];   // 16 KB
  int t = threadIdx.x;                 // 0..127 = output column
  int row0 = blockIdx.x * PROJ_ROWS;
  for (int i = t; i < PROJ_ROWS * D; i += 128) {
    int r = i >> 7, c = i & 127;
    int v = row0 + r;
    sE[r][c] = (v < V) ? embeds[(size_t)v * D + c] : 0.f;
  }
  __syncthreads();
  float bd = b1[t];
  float acc[PROJ_ROWS];
#pragma unroll
  for (int r = 0; r < PROJ_ROWS; ++r) acc[r] = bd;
#pragma unroll 4
  for (int k = 0; k < D; ++k) {
    float w = W1[k * D + t];           // coalesced; 64 KB, L2-resident
#pragma unroll
    for (int r = 0; r < PROJ_ROWS; ++r) acc[r] = fmaf(sE[r][k], w, acc[r]);
  }
  __syncthreads();                     // done with sE as input
#pragma unroll
  for (int r = 0; r < PROJ_ROWS; ++r) sE[r][t] = acc[r];
  __syncthreads();
  for (int i = t; i < PROJ_ROWS * 64; i += 128) {
    int r = i >> 6, l = i & 63;
    int v = row0 + r;
    if (v < V) P1p[(size_t)v * 64 + l] = pack_bf16x2(sE[r][l], sE[r][64 + l]);
  }
}

// ---------- K2: in-degree counts ----------
__global__ void k_count(const int* __restrict__ dst, int* __restrict__ counts) {
  int e = blockIdx.x * blockDim.x + threadIdx.x;
  if (e < NE) atomicAdd(&counts[dst[e]], 1);
}

// ---------- K3..K5: count -> exclusive scan (two-level) ----------
__global__ void k_chunksum(const int* __restrict__ counts, int* __restrict__ chunkSum) {
  __shared__ int red[256];
  int c = blockIdx.x, t = threadIdx.x;
  int base = c * CHUNK + t * 4;
  int s = 0;
#pragma unroll
  for (int i = 0; i < 4; ++i) { int idx = base + i; if (idx < NT) s += counts[idx]; }
  red[t] = s; __syncthreads();
  for (int off = 128; off > 0; off >>= 1) {
    if (t < off) red[t] += red[t + off];
    __syncthreads();
  }
  if (t == 0) chunkSum[c] = red[0];
}

__global__ void k_scanchunks(const int* __restrict__ chunkSum, int* __restrict__ chunkOff) {
  __shared__ int s[128];
  int t = threadIdx.x;                 // 128 threads
  int v = (t < NCHUNK) ? chunkSum[t] : 0;
  s[t] = v; __syncthreads();
  for (int off = 1; off < 128; off <<= 1) {
    int x = (t >= off) ? s[t - off] : 0;
    __syncthreads();
    s[t] += x;
    __syncthreads();
  }
  if (t < NCHUNK) chunkOff[t] = s[t] - v;   // exclusive
}

__global__ void k_scan_write(const int* __restrict__ counts, const int* __restrict__ chunkOff,
                             int* __restrict__ row_start) {
  __shared__ int s[256];
  int c = blockIdx.x, t = threadIdx.x;
  int base = c * CHUNK + t * 4;
  int c0 = 0, c1 = 0, c2 = 0, c3 = 0;
  if (base + 0 < NT) c0 = counts[base + 0];
  if (base + 1 < NT) c1 = counts[base + 1];
  if (base + 2 < NT) c2 = counts[base + 2];
  if (base + 3 < NT) c3 = counts[base + 3];
  int tsum = c0 + c1 + c2 + c3;
  s[t] = tsum; __syncthreads();
  for (int off = 1; off < 256; off <<= 1) {
    int x = (t >= off) ? s[t - off] : 0;
    __syncthreads();
    s[t] += x;
    __syncthreads();
  }
  int toff = s[t] - tsum + chunkOff[c];
  if (base + 0 < NT) row_start[base + 0] = toff;
  if (base + 1 < NT) row_start[base + 1] = toff + c0;
  if (base + 2 < NT) row_start[base + 2] = toff + c0 + c1;
  if (base + 3 < NT) row_start[base + 3] = toff + c0 + c1 + c2;
}

// ---------- K6: fill dst-CSR payload: (wid, w_bits, src, w_bits) ----------
__global__ void k_fill(const int* __restrict__ src, const int* __restrict__ dst,
                       const float* __restrict__ ew, const int* __restrict__ node_ids,
                       const int* __restrict__ rowD, int* __restrict__ curD,
                       int4* __restrict__ payDE) {
  int e = blockIdx.x * blockDim.x + threadIdx.x;
  if (e >= NE) return;
  int s = src[e], d = dst[e];
  int wb = __float_as_int(ew[e]);
  int pos = rowD[d] + atomicAdd(&curD[d], 1);
  payDE[pos] = make_int4(node_ids[s], wb, s, wb);
}

// ---------- K7: layer-1 aggregate + mean + leaky_relu -> h1p ----------
// one wave per dst node; lane l holds dims (l, l+64); depth-2 value prefetch
__global__ void k_agg1(const int4* __restrict__ payDE,
                       const int* __restrict__ rowD, const int* __restrict__ cntD,
                       const unsigned* __restrict__ P1p,
                       unsigned* __restrict__ h1p) {
  int n = blockIdx.x * 4 + (threadIdx.x >> 6);
  int l = threadIdx.x & 63;
  const int4* pp = payDE + rowD[n];
  int cnt = cntD[n];
  float ax = 0.f, ay = 0.f;
  int4 z = make_int4(0, 0, 0, 0);
  int4 p0 = (cnt > 0) ? pp[0] : z;
  int4 p1 = (cnt > 1) ? pp[1] : z;
  int4 p2 = (cnt > 2) ? pp[2] : z;
  unsigned v0 = (cnt > 0) ? P1p[(size_t)p0.x * 64 + l] : 0u;
  unsigned v1 = (cnt > 1) ? P1p[(size_t)p1.x * 64 + l] : 0u;
  for (int j = 0; j < cnt; ++j) {
    unsigned v2 = (j + 2 < cnt) ? P1p[(size_t)p2.x * 64 + l] : 0u;  // 2 ahead
    int4 p3 = (j + 3 < cnt) ? pp[j + 3] : z;                        // 3 ahead
    float w = __int_as_float(p0.y);
    float2 v = unpack_bf16x2(v0);
    ax = fmaf(w, v.x, ax);
    ay = fmaf(w, v.y, ay);
    p0 = p1; p1 = p2; p2 = p3; v0 = v1; v1 = v2;
  }
  float inv = (cnt > 0) ? (1.0f / (float)cnt) : 0.0f;
  float x0 = ax * inv, x1 = ay * inv;
  x0 = (x0 > 0.f) ? x0 : 0.01f * x0;   // leaky_relu(0)=0 so deg==0 rows stay 0
  x1 = (x1 > 0.f) ? x1 : 0.01f * x1;
  h1p[(size_t)n * 64 + l] = pack_bf16x2(x0, x1);
}

// ---------- K8: layer-2 dst-centric gather, fused per-graph pooling ----------
// block = 4 waves x NPW2 nodes, all within one graph; pool via regs -> LDS tree
// -> one global atomicAdd per lane per block.
#define NPW2 10
#define BLKS_PER_G (NODES_PER_GRAPH / (4 * NPW2))   // 50
__global__ void k_agg2(const int4* __restrict__ payDE,
                       const int* __restrict__ rowD, const int* __restrict__ cntD,
                       const unsigned* __restrict__ h1p,
                       float* __restrict__ pool) {
  int g = blockIdx.x / BLKS_PER_G;
  int chunk = blockIdx.x % BLKS_PER_G;
  int w = threadIdx.x >> 6, l = threadIdx.x & 63;
  int nbase = g * NODES_PER_GRAPH + chunk * (4 * NPW2) + w * NPW2;
  float sx = 0.f, sy = 0.f, sc = 0.f;
  int4 z = make_int4(0, 0, 0, 0);
  for (int i = 0; i < NPW2; ++i) {
    int n = nbase + i;
    const int4* pp = payDE + rowD[n];
    int cnt = cntD[n];
    if (cnt == 0) continue;
    float ax = 0.f, ay = 0.f, sw = 0.f;
    int4 p0 = pp[0];
    int4 p1 = (cnt > 1) ? pp[1] : z;
    int4 p2 = (cnt > 2) ? pp[2] : z;
    unsigned v0 = h1p[(size_t)p0.z * 64 + l];
    unsigned v1 = (cnt > 1) ? h1p[(size_t)p1.z * 64 + l] : 0u;
    for (int j = 0; j < cnt; ++j) {
      unsigned v2 = (j + 2 < cnt) ? h1p[(size_t)p2.z * 64 + l] : 0u;
      int4 p3 = (j + 3 < cnt) ? pp[j + 3] : z;
      float wgt = __int_as_float(p0.y);
      float2 v = unpack_bf16x2(v0);
      ax = fmaf(wgt, v.x, ax);
      ay = fmaf(wgt, v.y, ay);
      sw += wgt;
      p0 = p1; p1 = p2; p2 = p3; v0 = v1; v1 = v2;
    }
    float inv = 1.0f / (float)cnt;
    sx = fmaf(ax, inv, sx);
    sy = fmaf(ay, inv, sy);
    sc = fmaf(sw, inv, sc);
  }
  __shared__ float sS[4 * 128];
  __shared__ float sC[4];
  sS[w * 128 + l] = sx;
  sS[w * 128 + 64 + l] = sy;
  if (l == 0) sC[w] = sc;               // sc is wave-uniform: one lane only
  __syncthreads();
  int t = threadIdx.x;
  if (t < 128) {
    float v = sS[t] + sS[128 + t] + sS[256 + t] + sS[384 + t];
    atomicAdd(&pool[g * D + t], v);
  }
  if (t == 0) atomicAdd(&pool[B_GRAPHS * D + g], sC[0] + sC[1] + sC[2] + sC[3]);
}

// ---------- K9: head ----------
__global__ void k_final(const float* __restrict__ poolS, const float* __restrict__ poolC,
                        const float* __restrict__ W2, const float* __restrict__ b2,
                        const float* __restrict__ W_out, const float* __restrict__ b_out,
                        const float* __restrict__ y, float* __restrict__ out) {
  int t = threadIdx.x;  // 128 threads
  __shared__ float w2o[D];
  __shared__ float red[D];
  __shared__ float s2o_sh;
  __shared__ float logits[B_GRAPHS];
  float acc = 0.f;
  for (int d = 0; d < D; ++d) acc = fmaf(W2[t * D + d], W_out[d], acc);
  w2o[t] = acc;
  red[t] = b2[t] * W_out[t];
  __syncthreads();
  for (int off = 64; off > 0; off >>= 1) {
    if (t < off) red[t] += red[t + off];
    __syncthreads();
  }
  if (t == 0) s2o_sh = red[0];
  __syncthreads();
  float s2o = s2o_sh;
  float bout = b_out[0];
  const float invN = 1.0f / (float)NODES_PER_GRAPH;
  for (int g = 0; g < B_GRAPHS; ++g) {
    red[t] = poolS[g * D + t] * w2o[t];
    __syncthreads();
    for (int off = 64; off > 0; off >>= 1) {
      if (t < off) red[t] += red[t + off];
      __syncthreads();
    }
    if (t == 0) logits[g] = red[0] * invN + poolC[g] * invN * s2o + bout;
    __syncthreads();
  }
  float term = 0.f;
  if (t < B_GRAPHS) {
    float l = logits[t];
    out[1 + t] = 1.0f / (1.0f + expf(-l));            // y_pred
    term = fmaxf(l, 0.f) - l * y[t] + log1pf(expf(-fabsf(l)));
  }
  red[t] = term;
  __syncthreads();
  for (int off = 64; off > 0; off >>= 1) {
    if (t < off) red[t] += red[t + off];
    __syncthreads();
  }
  if (t == 0) out[0] = red[0] / (float)B_GRAPHS;      // loss
}

extern "C" void kernel_launch(void* const* d_in, const int* in_sizes, int n_in,
                              void* d_out, int out_size, void* d_ws, size_t ws_size,
                              hipStream_t stream) {
  const int*   node_ids = (const int*)d_in[0];
  const int*   src      = (const int*)d_in[1];
  const int*   dst      = (const int*)d_in[2];
  const float* ew       = (const float*)d_in[3];
  const float* y        = (const float*)d_in[4];
  const float* embeds   = (const float*)d_in[5];
  const float* W1       = (const float*)d_in[6];
  const float* b1       = (const float*)d_in[7];
  const float* W2       = (const float*)d_in[8];
  const float* b2       = (const float*)d_in[9];
  const float* W_out    = (const float*)d_in[10];
  const float* b_out    = (const float*)d_in[11];
  float* out = (float*)d_out;
  (void)in_sizes; (void)n_in; (void)out_size; (void)ws_size;

  char* ws = (char*)d_ws;
  size_t off = 0;
  auto alloc = [&](size_t bytes) {
    size_t r = off;
    off = (off + bytes + 511) & ~(size_t)511;
    return r;
  };
  // zero region (poisoned 0xAA before every call)
  size_t o_cntD  = alloc((size_t)NT * 4);
  size_t o_curD  = alloc((size_t)NT * 4);
  size_t o_pool  = alloc((size_t)POOL_N * 4);
  size_t zero_end = off;
  // non-zeroed
  size_t o_rowD  = alloc((size_t)NT * 4);
  size_t o_csum  = alloc(128 * 4);
  size_t o_coff  = alloc(128 * 4);
  size_t o_P1p   = alloc((size_t)V * 64 * 4);          // 3.84 MB
  size_t o_payDE = alloc((size_t)NE * 16);             // 25.6 MB
  size_t o_h1p   = alloc((size_t)NT * 64 * 4);         // 25.6 MB

  int*      cntD    = (int*)(ws + o_cntD);
  int*      curD    = (int*)(ws + o_curD);
  float*    pool    = (float*)(ws + o_pool);
  int*      rowD    = (int*)(ws + o_rowD);
  int*      chunkSum= (int*)(ws + o_csum);
  int*      chunkOff= (int*)(ws + o_coff);
  unsigned* P1p     = (unsigned*)(ws + o_P1p);
  int4*     payDE   = (int4*)(ws + o_payDE);
  unsigned* h1p     = (unsigned*)(ws + o_h1p);

  hipMemsetAsync(ws, 0, zero_end, stream);

  k_project<<<(V + PROJ_ROWS - 1) / PROJ_ROWS, 128, 0, stream>>>(embeds, W1, b1, P1p);
  k_count<<<(NE + 255) / 256, 256, 0, stream>>>(dst, cntD);
  k_chunksum<<<NCHUNK, 256, 0, stream>>>(cntD, chunkSum);
  k_scanchunks<<<1, 128, 0, stream>>>(chunkSum, chunkOff);
  k_scan_write<<<NCHUNK, 256, 0, stream>>>(cntD, chunkOff, rowD);
  k_fill<<<(NE + 255) / 256, 256, 0, stream>>>(src, dst, ew, node_ids, rowD, curD, payDE);
  k_agg1<<<NT / 4, 256, 0, stream>>>(payDE, rowD, cntD, P1p, h1p);
  k_agg2<<<B_GRAPHS * BLKS_PER_G, 256, 0, stream>>>(payDE, rowD, cntD, h1p, pool);
  k_final<<<1, 128, 0, stream>>>(pool, pool + B_GRAPHS * D, W2, b2, W_out, b_out, y, out);
}

// Round 5
// 652.538 us; speedup vs baseline: 2.6184x; 1.1591x over previous
//
#include <hip/hip_runtime.h>
#include <hip/hip_fp16.h>
#include <math.h>

#define NT 100000
#define B_GRAPHS 50
#define NE 1600000
#define V 15000
#define D 128
#define NODES_PER_GRAPH (NT / B_GRAPHS)   // 2000

#define CHUNK 1024
#define NCHUNK ((NT + CHUNK - 1) / CHUNK) // 98

#define POOL_N (B_GRAPHS * D + B_GRAPHS)  // 6450
#define PAY_CAP (NE + 3 * NT + 256)       // padded-to-4 CSR capacity

// ---- e5m2 helpers: code = top byte of fp16 (RN). decode = byte<<8 as half ----
__device__ __forceinline__ unsigned enc2_e5m2(float a, float b) {
  unsigned ha = __half_as_ushort(__float2half(a));
  unsigned hb = __half_as_ushort(__float2half(b));
  ha = ((ha + 0x7fu + ((ha >> 8) & 1u)) >> 8) & 0xffu;
  hb = ((hb + 0x7fu + ((hb >> 8) & 1u)) >> 8) & 0xffu;
  return ha | (hb << 8);
}
__device__ __forceinline__ unsigned enc4_e5m2(float a, float b, float c, float d) {
  return enc2_e5m2(a, b) | (enc2_e5m2(c, d) << 16);
}
__device__ __forceinline__ float4 dec4_e5m2(unsigned u) {
  unsigned hp0 = ((u & 0xffu) << 8) | ((u & 0xff00u) << 16);      // dims d, d+1
  unsigned hp1 = ((u >> 8) & 0xff00u) | (u & 0xff000000u);        // dims d+2, d+3
  __half2 h0 = *(__half2*)&hp0;
  __half2 h1 = *(__half2*)&hp1;
  float2 f0 = __half22float2(h0);
  float2 f1 = __half22float2(h1);
  return make_float4(f0.x, f0.y, f1.x, f1.y);
}

// ---------- K1: P1p8 = e5m2(embeds @ W1 + b1)  [V, 32 uints] ----------
#define PROJ_ROWS 32
__global__ void k_project(const float* __restrict__ embeds,
                          const float* __restrict__ W1,
                          const float* __restrict__ b1,
                          unsigned* __restrict__ P1p8) {
  __shared__ float sE[PROJ_ROWS][D];   // 16 KB
  int t = threadIdx.x;                 // 0..127 = output column
  int row0 = blockIdx.x * PROJ_ROWS;
  for (int i = t; i < PROJ_ROWS * D; i += 128) {
    int r = i >> 7, c = i & 127;
    int v = row0 + r;
    sE[r][c] = (v < V) ? embeds[(size_t)v * D + c] : 0.f;
  }
  __syncthreads();
  float bd = b1[t];
  float acc[PROJ_ROWS];
#pragma unroll
  for (int r = 0; r < PROJ_ROWS; ++r) acc[r] = bd;
#pragma unroll 4
  for (int k = 0; k < D; ++k) {
    float w = W1[k * D + t];           // coalesced; 64 KB, L2-resident
#pragma unroll
    for (int r = 0; r < PROJ_ROWS; ++r) acc[r] = fmaf(sE[r][k], w, acc[r]);
  }
  __syncthreads();                     // done with sE as input
#pragma unroll
  for (int r = 0; r < PROJ_ROWS; ++r) sE[r][t] = acc[r];
  __syncthreads();
  for (int i = t; i < PROJ_ROWS * 32; i += 128) {
    int r = i >> 5, li = i & 31;
    int v = row0 + r;
    if (v < V)
      P1p8[(size_t)v * 32 + li] =
          enc4_e5m2(sE[r][4 * li], sE[r][4 * li + 1], sE[r][4 * li + 2], sE[r][4 * li + 3]);
  }
}

// ---------- K2: in-degree counts ----------
__global__ void k_count(const int* __restrict__ dst, int* __restrict__ counts) {
  int e = blockIdx.x * blockDim.x + threadIdx.x;
  if (e < NE) atomicAdd(&counts[dst[e]], 1);
}

// ---------- K3..K5: padded-count exclusive scan (rows padded to x4) ----------
__global__ void k_chunksum(const int* __restrict__ counts, int* __restrict__ chunkSum) {
  __shared__ int red[256];
  int c = blockIdx.x, t = threadIdx.x;
  int base = c * CHUNK + t * 4;
  int s = 0;
#pragma unroll
  for (int i = 0; i < 4; ++i) {
    int idx = base + i;
    if (idx < NT) s += (counts[idx] + 3) & ~3;
  }
  red[t] = s; __syncthreads();
  for (int off = 128; off > 0; off >>= 1) {
    if (t < off) red[t] += red[t + off];
    __syncthreads();
  }
  if (t == 0) chunkSum[c] = red[0];
}

__global__ void k_scanchunks(const int* __restrict__ chunkSum, int* __restrict__ chunkOff) {
  __shared__ int s[128];
  int t = threadIdx.x;                 // 128 threads
  int v = (t < NCHUNK) ? chunkSum[t] : 0;
  s[t] = v; __syncthreads();
  for (int off = 1; off < 128; off <<= 1) {
    int x = (t >= off) ? s[t - off] : 0;
    __syncthreads();
    s[t] += x;
    __syncthreads();
  }
  if (t < NCHUNK) chunkOff[t] = s[t] - v;   // exclusive
}

__global__ void k_scan_write(const int* __restrict__ counts, const int* __restrict__ chunkOff,
                             int* __restrict__ row_start) {
  __shared__ int s[256];
  int c = blockIdx.x, t = threadIdx.x;
  int base = c * CHUNK + t * 4;
  int c0 = 0, c1 = 0, c2 = 0, c3 = 0;
  if (base + 0 < NT) c0 = (counts[base + 0] + 3) & ~3;
  if (base + 1 < NT) c1 = (counts[base + 1] + 3) & ~3;
  if (base + 2 < NT) c2 = (counts[base + 2] + 3) & ~3;
  if (base + 3 < NT) c3 = (counts[base + 3] + 3) & ~3;
  int tsum = c0 + c1 + c2 + c3;
  s[t] = tsum; __syncthreads();
  for (int off = 1; off < 256; off <<= 1) {
    int x = (t >= off) ? s[t - off] : 0;
    __syncthreads();
    s[t] += x;
    __syncthreads();
  }
  int toff = s[t] - tsum + chunkOff[c];
  if (base + 0 < NT) row_start[base + 0] = toff;
  if (base + 1 < NT) row_start[base + 1] = toff + c0;
  if (base + 2 < NT) row_start[base + 2] = toff + c0 + c1;
  if (base + 3 < NT) row_start[base + 3] = toff + c0 + c1 + c2;
}

// ---------- K6: fill padded dst-CSR payload: (w_bf16<<16 | wid, src) ----------
__global__ void k_fill(const int* __restrict__ src, const int* __restrict__ dst,
                       const float* __restrict__ ew, const int* __restrict__ node_ids,
                       const int* __restrict__ rowD, int* __restrict__ curD,
                       int2* __restrict__ pay) {
  int e = blockIdx.x * blockDim.x + threadIdx.x;
  if (e >= NE) return;
  int s = src[e], d = dst[e];
  unsigned uw = __float_as_uint(ew[e]);
  unsigned wb = (uw + 0x7fffu + ((uw >> 16) & 1u)) & 0xffff0000u;   // RN bf16 bits
  int pos = rowD[d] + atomicAdd(&curD[d], 1);
  pay[pos] = make_int2((int)(wb | (unsigned)node_ids[s]), s);
}

// ---- shared row-gather: 2 edges/iter (half-waves), scalar payloads, pipelined ----
template<bool USE_WID>
__device__ __forceinline__ int pick_idx(const int4& q, int half) {
  int lo = USE_WID ? (q.x & 0xffff) : q.y;
  int hi = USE_WID ? (q.z & 0xffff) : q.w;
  return half ? hi : lo;
}
__device__ __forceinline__ void consume2(const int4& q, unsigned v, int half,
                                         float& a0, float& a1, float& a2, float& a3,
                                         float& sw) {
  int wm = half ? q.z : q.x;
  float w = __uint_as_float((unsigned)wm & 0xffff0000u);
  float4 x = dec4_e5m2(v);
  a0 = fmaf(w, x.x, a0); a1 = fmaf(w, x.y, a1);
  a2 = fmaf(w, x.z, a2); a3 = fmaf(w, x.w, a3);
  sw += w;
}

template<bool USE_WID>
__device__ __forceinline__ void gather_row(const int2* __restrict__ pay,
                                           const unsigned* __restrict__ tab,
                                           int beg, int cnt, int li, int half,
                                           float& a0, float& a1, float& a2, float& a3,
                                           float& sw) {
  int G = (cnt + 3) >> 2;                       // groups of 4 edges (rows padded)
  const int4* __restrict__ pp = (const int4*)(pay + beg);
  int4 z = make_int4(0, 0, 0, 0);
  int4 pa0, pb0, pa1, pb1, pa2, pb2;
  pa0 = (0 < G) ? pp[0] : z;  pb0 = (0 < G) ? pp[1] : z;
  pa1 = (1 < G) ? pp[2] : z;  pb1 = (1 < G) ? pp[3] : z;
  pa2 = (2 < G) ? pp[4] : z;  pb2 = (2 < G) ? pp[5] : z;
  unsigned vc0 = 0, vc1 = 0, vm0 = 0, vm1 = 0;
  if (0 < G) {
    vc0 = tab[(size_t)pick_idx<USE_WID>(pa0, half) * 32 + li];
    vc1 = tab[(size_t)pick_idx<USE_WID>(pb0, half) * 32 + li];
  }
  if (1 < G) {
    vm0 = tab[(size_t)pick_idx<USE_WID>(pa1, half) * 32 + li];
    vm1 = tab[(size_t)pick_idx<USE_WID>(pb1, half) * 32 + li];
  }
  for (int g = 0; g < G; ++g) {
    int4 pa3 = (g + 3 < G) ? pp[2 * g + 6] : z;
    int4 pb3 = (g + 3 < G) ? pp[2 * g + 7] : z;
    unsigned vn0 = 0, vn1 = 0;
    if (g + 2 < G) {
      vn0 = tab[(size_t)pick_idx<USE_WID>(pa2, half) * 32 + li];
      vn1 = tab[(size_t)pick_idx<USE_WID>(pb2, half) * 32 + li];
    }
    consume2(pa0, vc0, half, a0, a1, a2, a3, sw);
    consume2(pb0, vc1, half, a0, a1, a2, a3, sw);
    pa0 = pa1; pb0 = pb1; pa1 = pa2; pb1 = pb2; pa2 = pa3; pb2 = pb3;
    vc0 = vm0; vc1 = vm1; vm0 = vn0; vm1 = vn1;
  }
}

// ---------- K7: layer-1 aggregate + mean + leaky -> h1p8 (e5m2) ----------
__global__ void k_agg1(const int2* __restrict__ pay,
                       const int* __restrict__ rowD, const int* __restrict__ cntD,
                       const unsigned* __restrict__ P1p8,
                       unsigned* __restrict__ h1p8) {
  int n = blockIdx.x * 4 + (threadIdx.x >> 6);
  int lane = threadIdx.x & 63;
  int li = lane & 31, half = lane >> 5;
  int beg = __builtin_amdgcn_readfirstlane(rowD[n]);
  int cnt = __builtin_amdgcn_readfirstlane(cntD[n]);
  float a0 = 0.f, a1 = 0.f, a2 = 0.f, a3 = 0.f, sw = 0.f;
  gather_row<true>(pay, P1p8, beg, cnt, li, half, a0, a1, a2, a3, sw);
  a0 += __shfl_down(a0, 32);
  a1 += __shfl_down(a1, 32);
  a2 += __shfl_down(a2, 32);
  a3 += __shfl_down(a3, 32);
  if (lane < 32) {
    float inv = (cnt > 0) ? (1.0f / (float)cnt) : 0.0f;
    float x0 = a0 * inv, x1 = a1 * inv, x2 = a2 * inv, x3 = a3 * inv;
    x0 = (x0 > 0.f) ? x0 : 0.01f * x0;     // leaky_relu(0)=0 keeps deg==0 rows 0
    x1 = (x1 > 0.f) ? x1 : 0.01f * x1;
    x2 = (x2 > 0.f) ? x2 : 0.01f * x2;
    x3 = (x3 > 0.f) ? x3 : 0.01f * x3;
    h1p8[(size_t)n * 32 + li] = enc4_e5m2(x0, x1, x2, x3);
  }
}

// ---------- K8: layer-2 gather fused with per-graph pooling ----------
#define NPW2 10
#define BLKS_PER_G (NODES_PER_GRAPH / (4 * NPW2))   // 50
__global__ void k_agg2(const int2* __restrict__ pay,
                       const int* __restrict__ rowD, const int* __restrict__ cntD,
                       const unsigned* __restrict__ h1p8,
                       float* __restrict__ pool) {
  int g = blockIdx.x / BLKS_PER_G;
  int chunk = blockIdx.x % BLKS_PER_G;
  int w = threadIdx.x >> 6, lane = threadIdx.x & 63;
  int li = lane & 31, half = lane >> 5;
  int nbase = g * NODES_PER_GRAPH + chunk * (4 * NPW2) + w * NPW2;
  float s0 = 0.f, s1 = 0.f, s2 = 0.f, s3 = 0.f, sc = 0.f;
  for (int i = 0; i < NPW2; ++i) {
    int n = nbase + i;
    int beg = __builtin_amdgcn_readfirstlane(rowD[n]);
    int cnt = __builtin_amdgcn_readfirstlane(cntD[n]);
    if (cnt == 0) continue;                     // uniform branch
    float a0 = 0.f, a1 = 0.f, a2 = 0.f, a3 = 0.f, sw = 0.f;
    gather_row<false>(pay, h1p8, beg, cnt, li, half, a0, a1, a2, a3, sw);
    float inv = 1.0f / (float)cnt;
    s0 = fmaf(a0, inv, s0); s1 = fmaf(a1, inv, s1);
    s2 = fmaf(a2, inv, s2); s3 = fmaf(a3, inv, s3);
    sc = fmaf(sw, inv, sc);
  }
  s0 += __shfl_down(s0, 32);
  s1 += __shfl_down(s1, 32);
  s2 += __shfl_down(s2, 32);
  s3 += __shfl_down(s3, 32);
  sc += __shfl_down(sc, 32);
  __shared__ float sS[4 * 128];
  __shared__ float sC[4];
  if (lane < 32) {
    sS[w * 128 + 4 * li + 0] = s0;
    sS[w * 128 + 4 * li + 1] = s1;
    sS[w * 128 + 4 * li + 2] = s2;
    sS[w * 128 + 4 * li + 3] = s3;
  }
  if (lane == 0) sC[w] = sc;
  __syncthreads();
  int t = threadIdx.x;
  if (t < 128) {
    float v = sS[t] + sS[128 + t] + sS[256 + t] + sS[384 + t];
    atomicAdd(&pool[g * D + t], v);
  }
  if (t == 0) atomicAdd(&pool[B_GRAPHS * D + g], sC[0] + sC[1] + sC[2] + sC[3]);
}

// ---------- K9: head ----------
__global__ void k_final(const float* __restrict__ poolS, const float* __restrict__ poolC,
                        const float* __restrict__ W2, const float* __restrict__ b2,
                        const float* __restrict__ W_out, const float* __restrict__ b_out,
                        const float* __restrict__ y, float* __restrict__ out) {
  int t = threadIdx.x;  // 128 threads
  __shared__ float w2o[D];
  __shared__ float red[D];
  __shared__ float s2o_sh;
  __shared__ float logits[B_GRAPHS];
  float acc = 0.f;
  for (int d = 0; d < D; ++d) acc = fmaf(W2[t * D + d], W_out[d], acc);
  w2o[t] = acc;
  red[t] = b2[t] * W_out[t];
  __syncthreads();
  for (int off = 64; off > 0; off >>= 1) {
    if (t < off) red[t] += red[t + off];
    __syncthreads();
  }
  if (t == 0) s2o_sh = red[0];
  __syncthreads();
  float s2o = s2o_sh;
  float bout = b_out[0];
  const float invN = 1.0f / (float)NODES_PER_GRAPH;
  for (int g = 0; g < B_GRAPHS; ++g) {
    red[t] = poolS[g * D + t] * w2o[t];
    __syncthreads();
    for (int off = 64; off > 0; off >>= 1) {
      if (t < off) red[t] += red[t + off];
      __syncthreads();
    }
    if (t == 0) logits[g] = red[0] * invN + poolC[g] * invN * s2o + bout;
    __syncthreads();
  }
  float term = 0.f;
  if (t < B_GRAPHS) {
    float l = logits[t];
    out[1 + t] = 1.0f / (1.0f + expf(-l));            // y_pred
    term = fmaxf(l, 0.f) - l * y[t] + log1pf(expf(-fabsf(l)));
  }
  red[t] = term;
  __syncthreads();
  for (int off = 64; off > 0; off >>= 1) {
    if (t < off) red[t] += red[t + off];
    __syncthreads();
  }
  if (t == 0) out[0] = red[0] / (float)B_GRAPHS;      // loss
}

extern "C" void kernel_launch(void* const* d_in, const int* in_sizes, int n_in,
                              void* d_out, int out_size, void* d_ws, size_t ws_size,
                              hipStream_t stream) {
  const int*   node_ids = (const int*)d_in[0];
  const int*   src      = (const int*)d_in[1];
  const int*   dst      = (const int*)d_in[2];
  const float* ew       = (const float*)d_in[3];
  const float* y        = (const float*)d_in[4];
  const float* embeds   = (const float*)d_in[5];
  const float* W1       = (const float*)d_in[6];
  const float* b1       = (const float*)d_in[7];
  const float* W2       = (const float*)d_in[8];
  const float* b2       = (const float*)d_in[9];
  const float* W_out    = (const float*)d_in[10];
  const float* b_out    = (const float*)d_in[11];
  float* out = (float*)d_out;
  (void)in_sizes; (void)n_in; (void)out_size; (void)ws_size;

  char* ws = (char*)d_ws;
  size_t off = 0;
  auto alloc = [&](size_t bytes) {
    size_t r = off;
    off = (off + bytes + 511) & ~(size_t)511;
    return r;
  };
  // zero region (poisoned 0xAA before every call)
  size_t o_cntD  = alloc((size_t)NT * 4);
  size_t o_curD  = alloc((size_t)NT * 4);
  size_t o_pool  = alloc((size_t)POOL_N * 4);
  size_t o_pay   = alloc((size_t)PAY_CAP * 8);         // 15.2 MB (padding must be 0)
  size_t zero_end = off;
  // non-zeroed
  size_t o_rowD  = alloc((size_t)NT * 4);
  size_t o_csum  = alloc(128 * 4);
  size_t o_coff  = alloc(128 * 4);
  size_t o_P1p8  = alloc((size_t)V * 32 * 4);          // 1.92 MB
  size_t o_h1p8  = alloc((size_t)NT * 32 * 4);         // 12.8 MB

  int*      cntD    = (int*)(ws + o_cntD);
  int*      curD    = (int*)(ws + o_curD);
  float*    pool    = (float*)(ws + o_pool);
  int2*     pay     = (int2*)(ws + o_pay);
  int*      rowD    = (int*)(ws + o_rowD);
  int*      chunkSum= (int*)(ws + o_csum);
  int*      chunkOff= (int*)(ws + o_coff);
  unsigned* P1p8    = (unsigned*)(ws + o_P1p8);
  unsigned* h1p8    = (unsigned*)(ws + o_h1p8);

  hipMemsetAsync(ws, 0, zero_end, stream);

  k_project<<<(V + PROJ_ROWS - 1) / PROJ_ROWS, 128, 0, stream>>>(embeds, W1, b1, P1p8);
  k_count<<<(NE + 255) / 256, 256, 0, stream>>>(dst, cntD);
  k_chunksum<<<NCHUNK, 256, 0, stream>>>(cntD, chunkSum);
  k_scanchunks<<<1, 128, 0, stream>>>(chunkSum, chunkOff);
  k_scan_write<<<NCHUNK, 256, 0, stream>>>(cntD, chunkOff, rowD);
  k_fill<<<(NE + 255) / 256, 256, 0, stream>>>(src, dst, ew, node_ids, rowD, curD, pay);
  k_agg1<<<NT / 4, 256, 0, stream>>>(pay, rowD, cntD, P1p8, h1p8);
  k_agg2<<<B_GRAPHS * BLKS_PER_G, 256, 0, stream>>>(pay, rowD, cntD, h1p8, pool);
  k_final<<<1, 128, 0, stream>>>(pool, pool + B_GRAPHS * D, W2, b2, W_out, b_out, y, out);
}

// Round 6
// 543.303 us; speedup vs baseline: 3.1448x; 1.2011x over previous
//
#include <hip/hip_runtime.h>
#include <hip/hip_fp16.h>
#include <math.h>

#define NT 100000
#define B_GRAPHS 50
#define NE 1600000
#define V 15000
#define D 128
#define NODES_PER_GRAPH (NT / B_GRAPHS)   // 2000

#define CHUNK 1024
#define NCHUNK ((NT + CHUNK - 1) / CHUNK) // 98

#define POOL_N (B_GRAPHS * D + B_GRAPHS)  // 6450
#define PAY_CAP (NE + 3 * NT + 256)       // padded-to-4 CSR capacity

// ---- e5m2 helpers: code = top byte of fp16 (RN). decode = byte<<8 as half ----
__device__ __forceinline__ unsigned enc2_e5m2(float a, float b) {
  unsigned ha = __half_as_ushort(__float2half(a));
  unsigned hb = __half_as_ushort(__float2half(b));
  ha = ((ha + 0x7fu + ((ha >> 8) & 1u)) >> 8) & 0xffu;
  hb = ((hb + 0x7fu + ((hb >> 8) & 1u)) >> 8) & 0xffu;
  return ha | (hb << 8);
}
__device__ __forceinline__ unsigned enc4_e5m2(float a, float b, float c, float d) {
  return enc2_e5m2(a, b) | (enc2_e5m2(c, d) << 16);
}
__device__ __forceinline__ float4 dec4_e5m2(unsigned u) {
  unsigned hp0 = ((u & 0xffu) << 8) | ((u & 0xff00u) << 16);      // dims d, d+1
  unsigned hp1 = ((u >> 8) & 0xff00u) | (u & 0xff000000u);        // dims d+2, d+3
  __half2 h0 = *(__half2*)&hp0;
  __half2 h1 = *(__half2*)&hp1;
  float2 f0 = __half22float2(h0);
  float2 f1 = __half22float2(h1);
  return make_float4(f0.x, f0.y, f1.x, f1.y);
}

// ---------- K1: P1p8 = e5m2(embeds @ W1 + b1)  [V, 32 uints] ----------
// 938 blocks x 256 thr, 16 rows/block, 8 acc/thread: occupancy-first design.
// sE[r][k] is wave-uniform (LDS broadcast, free); W1 load coalesced, 8x reuse.
#define PR 16
__global__ __launch_bounds__(256, 8)
void k_project(const float* __restrict__ embeds,
               const float* __restrict__ W1,
               const float* __restrict__ b1,
               unsigned* __restrict__ P1p8) {
  __shared__ float sE[PR][D];          // 8 KB
  __shared__ float sO[PR][D];          // 8 KB
  int t = threadIdx.x;
  int row0 = blockIdx.x * PR;
  for (int i = t; i < PR * D; i += 256) {
    int r = i >> 7, c = i & 127;
    int v = row0 + r;
    sE[r][c] = (v < V) ? embeds[(size_t)v * D + c] : 0.f;
  }
  __syncthreads();
  int c = t & 127, rg = (t >> 7) * 8;  // this thread: col c, rows rg..rg+7
  float bd = b1[c];
  float acc[8];
#pragma unroll
  for (int r = 0; r < 8; ++r) acc[r] = bd;
#pragma unroll 4
  for (int k = 0; k < D; ++k) {
    float w = W1[k * D + c];           // coalesced; L2-resident (64 KB)
#pragma unroll
    for (int r = 0; r < 8; ++r) acc[r] = fmaf(sE[rg + r][k], w, acc[r]);
  }
#pragma unroll
  for (int r = 0; r < 8; ++r) sO[rg + r][c] = acc[r];
  __syncthreads();
  for (int i = t; i < PR * 32; i += 256) {
    int r = i >> 5, li = i & 31;
    int v = row0 + r;
    if (v < V)
      P1p8[(size_t)v * 32 + li] =
          enc4_e5m2(sO[r][4 * li], sO[r][4 * li + 1], sO[r][4 * li + 2], sO[r][4 * li + 3]);
  }
}

// ---------- K2: in-degree counts ----------
__global__ void k_count(const int* __restrict__ dst, int* __restrict__ counts) {
  int e = blockIdx.x * blockDim.x + threadIdx.x;
  if (e < NE) atomicAdd(&counts[dst[e]], 1);
}

// ---------- K3..K5: padded-count exclusive scan (rows padded to x4) ----------
__global__ void k_chunksum(const int* __restrict__ counts, int* __restrict__ chunkSum) {
  __shared__ int red[256];
  int c = blockIdx.x, t = threadIdx.x;
  int base = c * CHUNK + t * 4;
  int s = 0;
#pragma unroll
  for (int i = 0; i < 4; ++i) {
    int idx = base + i;
    if (idx < NT) s += (counts[idx] + 3) & ~3;
  }
  red[t] = s; __syncthreads();
  for (int off = 128; off > 0; off >>= 1) {
    if (t < off) red[t] += red[t + off];
    __syncthreads();
  }
  if (t == 0) chunkSum[c] = red[0];
}

__global__ void k_scanchunks(const int* __restrict__ chunkSum, int* __restrict__ chunkOff) {
  __shared__ int s[128];
  int t = threadIdx.x;                 // 128 threads
  int v = (t < NCHUNK) ? chunkSum[t] : 0;
  s[t] = v; __syncthreads();
  for (int off = 1; off < 128; off <<= 1) {
    int x = (t >= off) ? s[t - off] : 0;
    __syncthreads();
    s[t] += x;
    __syncthreads();
  }
  if (t < NCHUNK) chunkOff[t] = s[t] - v;   // exclusive
}

__global__ void k_scan_write(const int* __restrict__ counts, const int* __restrict__ chunkOff,
                             int* __restrict__ row_start) {
  __shared__ int s[256];
  int c = blockIdx.x, t = threadIdx.x;
  int base = c * CHUNK + t * 4;
  int c0 = 0, c1 = 0, c2 = 0, c3 = 0;
  if (base + 0 < NT) c0 = (counts[base + 0] + 3) & ~3;
  if (base + 1 < NT) c1 = (counts[base + 1] + 3) & ~3;
  if (base + 2 < NT) c2 = (counts[base + 2] + 3) & ~3;
  if (base + 3 < NT) c3 = (counts[base + 3] + 3) & ~3;
  int tsum = c0 + c1 + c2 + c3;
  s[t] = tsum; __syncthreads();
  for (int off = 1; off < 256; off <<= 1) {
    int x = (t >= off) ? s[t - off] : 0;
    __syncthreads();
    s[t] += x;
    __syncthreads();
  }
  int toff = s[t] - tsum + chunkOff[c];
  if (base + 0 < NT) row_start[base + 0] = toff;
  if (base + 1 < NT) row_start[base + 1] = toff + c0;
  if (base + 2 < NT) row_start[base + 2] = toff + c0 + c1;
  if (base + 3 < NT) row_start[base + 3] = toff + c0 + c1 + c2;
}

// ---------- K6: fill padded dst-CSR payload: (w_bf16<<16 | wid, src) ----------
__global__ void k_fill(const int* __restrict__ src, const int* __restrict__ dst,
                       const float* __restrict__ ew, const int* __restrict__ node_ids,
                       const int* __restrict__ rowD, int* __restrict__ curD,
                       int2* __restrict__ pay) {
  int e = blockIdx.x * blockDim.x + threadIdx.x;
  if (e >= NE) return;
  int s = src[e], d = dst[e];
  unsigned uw = __float_as_uint(ew[e]);
  unsigned wb = (uw + 0x7fffu + ((uw >> 16) & 1u)) & 0xffff0000u;   // RN bf16 bits
  int pos = rowD[d] + atomicAdd(&curD[d], 1);
  pay[pos] = make_int2((int)(wb | (unsigned)node_ids[s]), s);
}

// ---- shared row-gather: 2 edges/iter (half-waves), scalar payloads, pipelined ----
template<bool USE_WID>
__device__ __forceinline__ int pick_idx(const int4& q, int half) {
  int lo = USE_WID ? (q.x & 0xffff) : q.y;
  int hi = USE_WID ? (q.z & 0xffff) : q.w;
  return half ? hi : lo;
}
__device__ __forceinline__ void consume2(const int4& q, unsigned v, int half,
                                         float& a0, float& a1, float& a2, float& a3,
                                         float& sw) {
  int wm = half ? q.z : q.x;
  float w = __uint_as_float((unsigned)wm & 0xffff0000u);
  float4 x = dec4_e5m2(v);
  a0 = fmaf(w, x.x, a0); a1 = fmaf(w, x.y, a1);
  a2 = fmaf(w, x.z, a2); a3 = fmaf(w, x.w, a3);
  sw += w;
}

template<bool USE_WID>
__device__ __forceinline__ void gather_row(const int2* __restrict__ pay,
                                           const unsigned* __restrict__ tab,
                                           int beg, int cnt, int li, int half,
                                           float& a0, float& a1, float& a2, float& a3,
                                           float& sw) {
  int G = (cnt + 3) >> 2;                       // groups of 4 edges (rows padded)
  const int4* __restrict__ pp = (const int4*)(pay + beg);
  int4 z = make_int4(0, 0, 0, 0);
  int4 pa0, pb0, pa1, pb1, pa2, pb2;
  pa0 = (0 < G) ? pp[0] : z;  pb0 = (0 < G) ? pp[1] : z;
  pa1 = (1 < G) ? pp[2] : z;  pb1 = (1 < G) ? pp[3] : z;
  pa2 = (2 < G) ? pp[4] : z;  pb2 = (2 < G) ? pp[5] : z;
  unsigned vc0 = 0, vc1 = 0, vm0 = 0, vm1 = 0;
  if (0 < G) {
    vc0 = tab[(size_t)pick_idx<USE_WID>(pa0, half) * 32 + li];
    vc1 = tab[(size_t)pick_idx<USE_WID>(pb0, half) * 32 + li];
  }
  if (1 < G) {
    vm0 = tab[(size_t)pick_idx<USE_WID>(pa1, half) * 32 + li];
    vm1 = tab[(size_t)pick_idx<USE_WID>(pb1, half) * 32 + li];
  }
  for (int g = 0; g < G; ++g) {
    int4 pa3 = (g + 3 < G) ? pp[2 * g + 6] : z;
    int4 pb3 = (g + 3 < G) ? pp[2 * g + 7] : z;
    unsigned vn0 = 0, vn1 = 0;
    if (g + 2 < G) {
      vn0 = tab[(size_t)pick_idx<USE_WID>(pa2, half) * 32 + li];
      vn1 = tab[(size_t)pick_idx<USE_WID>(pb2, half) * 32 + li];
    }
    consume2(pa0, vc0, half, a0, a1, a2, a3, sw);
    consume2(pb0, vc1, half, a0, a1, a2, a3, sw);
    pa0 = pa1; pb0 = pb1; pa1 = pa2; pb1 = pb2; pa2 = pa3; pb2 = pb3;
    vc0 = vm0; vc1 = vm1; vm0 = vn0; vm1 = vn1;
  }
}

// ---------- K7: layer-1 aggregate + mean + leaky -> h1p8 (e5m2) ----------
__global__ void k_agg1(const int2* __restrict__ pay,
                       const int* __restrict__ rowD, const int* __restrict__ cntD,
                       const unsigned* __restrict__ P1p8,
                       unsigned* __restrict__ h1p8) {
  int n = blockIdx.x * 4 + (threadIdx.x >> 6);
  int lane = threadIdx.x & 63;
  int li = lane & 31, half = lane >> 5;
  int beg = __builtin_amdgcn_readfirstlane(rowD[n]);
  int cnt = __builtin_amdgcn_readfirstlane(cntD[n]);
  float a0 = 0.f, a1 = 0.f, a2 = 0.f, a3 = 0.f, sw = 0.f;
  gather_row<true>(pay, P1p8, beg, cnt, li, half, a0, a1, a2, a3, sw);
  a0 += __shfl_down(a0, 32);
  a1 += __shfl_down(a1, 32);
  a2 += __shfl_down(a2, 32);
  a3 += __shfl_down(a3, 32);
  if (lane < 32) {
    float inv = (cnt > 0) ? (1.0f / (float)cnt) : 0.0f;
    float x0 = a0 * inv, x1 = a1 * inv, x2 = a2 * inv, x3 = a3 * inv;
    x0 = (x0 > 0.f) ? x0 : 0.01f * x0;     // leaky_relu(0)=0 keeps deg==0 rows 0
    x1 = (x1 > 0.f) ? x1 : 0.01f * x1;
    x2 = (x2 > 0.f) ? x2 : 0.01f * x2;
    x3 = (x3 > 0.f) ? x3 : 0.01f * x3;
    h1p8[(size_t)n * 32 + li] = enc4_e5m2(x0, x1, x2, x3);
  }
}

// ---------- K8: layer-2 gather fused with per-graph pooling ----------
#define NPW2 10
#define BLKS_PER_G (NODES_PER_GRAPH / (4 * NPW2))   // 50
__global__ void k_agg2(const int2* __restrict__ pay,
                       const int* __restrict__ rowD, const int* __restrict__ cntD,
                       const unsigned* __restrict__ h1p8,
                       float* __restrict__ pool) {
  int g = blockIdx.x / BLKS_PER_G;
  int chunk = blockIdx.x % BLKS_PER_G;
  int w = threadIdx.x >> 6, lane = threadIdx.x & 63;
  int li = lane & 31, half = lane >> 5;
  int nbase = g * NODES_PER_GRAPH + chunk * (4 * NPW2) + w * NPW2;
  float s0 = 0.f, s1 = 0.f, s2 = 0.f, s3 = 0.f, sc = 0.f;
  for (int i = 0; i < NPW2; ++i) {
    int n = nbase + i;
    int beg = __builtin_amdgcn_readfirstlane(rowD[n]);
    int cnt = __builtin_amdgcn_readfirstlane(cntD[n]);
    if (cnt == 0) continue;                     // uniform branch
    float a0 = 0.f, a1 = 0.f, a2 = 0.f, a3 = 0.f, sw = 0.f;
    gather_row<false>(pay, h1p8, beg, cnt, li, half, a0, a1, a2, a3, sw);
    float inv = 1.0f / (float)cnt;
    s0 = fmaf(a0, inv, s0); s1 = fmaf(a1, inv, s1);
    s2 = fmaf(a2, inv, s2); s3 = fmaf(a3, inv, s3);
    sc = fmaf(sw, inv, sc);
  }
  s0 += __shfl_down(s0, 32);
  s1 += __shfl_down(s1, 32);
  s2 += __shfl_down(s2, 32);
  s3 += __shfl_down(s3, 32);
  sc += __shfl_down(sc, 32);
  __shared__ float sS[4 * 128];
  __shared__ float sC[4];
  if (lane < 32) {
    sS[w * 128 + 4 * li + 0] = s0;
    sS[w * 128 + 4 * li + 1] = s1;
    sS[w * 128 + 4 * li + 2] = s2;
    sS[w * 128 + 4 * li + 3] = s3;
  }
  if (lane == 0) sC[w] = sc;
  __syncthreads();
  int t = threadIdx.x;
  if (t < 128) {
    float v = sS[t] + sS[128 + t] + sS[256 + t] + sS[384 + t];
    atomicAdd(&pool[g * D + t], v);
  }
  if (t == 0) atomicAdd(&pool[B_GRAPHS * D + g], sC[0] + sC[1] + sC[2] + sC[3]);
}

// ---------- K9: head ----------
__global__ void k_final(const float* __restrict__ poolS, const float* __restrict__ poolC,
                        const float* __restrict__ W2, const float* __restrict__ b2,
                        const float* __restrict__ W_out, const float* __restrict__ b_out,
                        const float* __restrict__ y, float* __restrict__ out) {
  int t = threadIdx.x;  // 128 threads
  __shared__ float w2o[D];
  __shared__ float red[D];
  __shared__ float s2o_sh;
  __shared__ float logits[B_GRAPHS];
  float acc = 0.f;
  for (int d = 0; d < D; ++d) acc = fmaf(W2[t * D + d], W_out[d], acc);
  w2o[t] = acc;
  red[t] = b2[t] * W_out[t];
  __syncthreads();
  for (int off = 64; off > 0; off >>= 1) {
    if (t < off) red[t] += red[t + off];
    __syncthreads();
  }
  if (t == 0) s2o_sh = red[0];
  __syncthreads();
  float s2o = s2o_sh;
  float bout = b_out[0];
  const float invN = 1.0f / (float)NODES_PER_GRAPH;
  for (int g = 0; g < B_GRAPHS; ++g) {
    red[t] = poolS[g * D + t] * w2o[t];
    __syncthreads();
    for (int off = 64; off > 0; off >>= 1) {
      if (t < off) red[t] += red[t + off];
      __syncthreads();
    }
    if (t == 0) logits[g] = red[0] * invN + poolC[g] * invN * s2o + bout;
    __syncthreads();
  }
  float term = 0.f;
  if (t < B_GRAPHS) {
    float l = logits[t];
    out[1 + t] = 1.0f / (1.0f + expf(-l));            // y_pred
    term = fmaxf(l, 0.f) - l * y[t] + log1pf(expf(-fabsf(l)));
  }
  red[t] = term;
  __syncthreads();
  for (int off = 64; off > 0; off >>= 1) {
    if (t < off) red[t] += red[t + off];
    __syncthreads();
  }
  if (t == 0) out[0] = red[0] / (float)B_GRAPHS;      // loss
}

extern "C" void kernel_launch(void* const* d_in, const int* in_sizes, int n_in,
                              void* d_out, int out_size, void* d_ws, size_t ws_size,
                              hipStream_t stream) {
  const int*   node_ids = (const int*)d_in[0];
  const int*   src      = (const int*)d_in[1];
  const int*   dst      = (const int*)d_in[2];
  const float* ew       = (const float*)d_in[3];
  const float* y        = (const float*)d_in[4];
  const float* embeds   = (const float*)d_in[5];
  const float* W1       = (const float*)d_in[6];
  const float* b1       = (const float*)d_in[7];
  const float* W2       = (const float*)d_in[8];
  const float* b2       = (const float*)d_in[9];
  const float* W_out    = (const float*)d_in[10];
  const float* b_out    = (const float*)d_in[11];
  float* out = (float*)d_out;
  (void)in_sizes; (void)n_in; (void)out_size; (void)ws_size;

  char* ws = (char*)d_ws;
  size_t off = 0;
  auto alloc = [&](size_t bytes) {
    size_t r = off;
    off = (off + bytes + 511) & ~(size_t)511;
    return r;
  };
  // zero region (poisoned 0xAA before every call)
  size_t o_cntD  = alloc((size_t)NT * 4);
  size_t o_curD  = alloc((size_t)NT * 4);
  size_t o_pool  = alloc((size_t)POOL_N * 4);
  size_t o_pay   = alloc((size_t)PAY_CAP * 8);         // 15.2 MB (padding must be 0)
  size_t zero_end = off;
  // non-zeroed
  size_t o_rowD  = alloc((size_t)NT * 4);
  size_t o_csum  = alloc(128 * 4);
  size_t o_coff  = alloc(128 * 4);
  size_t o_P1p8  = alloc((size_t)V * 32 * 4);          // 1.92 MB
  size_t o_h1p8  = alloc((size_t)NT * 32 * 4);         // 12.8 MB

  int*      cntD    = (int*)(ws + o_cntD);
  int*      curD    = (int*)(ws + o_curD);
  float*    pool    = (float*)(ws + o_pool);
  int2*     pay     = (int2*)(ws + o_pay);
  int*      rowD    = (int*)(ws + o_rowD);
  int*      chunkSum= (int*)(ws + o_csum);
  int*      chunkOff= (int*)(ws + o_coff);
  unsigned* P1p8    = (unsigned*)(ws + o_P1p8);
  unsigned* h1p8    = (unsigned*)(ws + o_h1p8);

  hipMemsetAsync(ws, 0, zero_end, stream);

  k_project<<<(V + PR - 1) / PR, 256, 0, stream>>>(embeds, W1, b1, P1p8);
  k_count<<<(NE + 255) / 256, 256, 0, stream>>>(dst, cntD);
  k_chunksum<<<NCHUNK, 256, 0, stream>>>(cntD, chunkSum);
  k_scanchunks<<<1, 128, 0, stream>>>(chunkSum, chunkOff);
  k_scan_write<<<NCHUNK, 256, 0, stream>>>(cntD, chunkOff, rowD);
  k_fill<<<(NE + 255) / 256, 256, 0, stream>>>(src, dst, ew, node_ids, rowD, curD, pay);
  k_agg1<<<NT / 4, 256, 0, stream>>>(pay, rowD, cntD, P1p8, h1p8);
  k_agg2<<<B_GRAPHS * BLKS_PER_G, 256, 0, stream>>>(pay, rowD, cntD, h1p8, pool);
  k_final<<<1, 128, 0, stream>>>(pool, pool + B_GRAPHS * D, W2, b2, W_out, b_out, y, out);
}